// Round 7
// baseline (237.762 us; speedup 1.0000x reference)
//
#include <hip/hip_runtime.h>

// MHA: B=2 S=2048 D=1024 H=16 DH=64.  All GEMMs bf16 MFMA, fp32 acc.
// R7: attn: MFMA16 (16x16x16bf16_1k) measured ~15 cyc vs MFMA32's ~4.85 ->
//     PV rebuilt on MFMA32 via shuffle-built K=32 P^T fragments (8 shfl +
//     4 cndmask per 32-key chunk); l-sum via ones-MFMA32 on the same frags.
//     No MFMA16 anywhere.  GEMM kernels unchanged from R6 (BK=64 + swizzle).
// ws: xb 8MB @0 | wq/wk/wv/wo bf16 2MB each @8/10/12/14MB | q 8MB @16MB |
//     k 8MB @24MB | v^T 8MB @32MB [b,h,dh,s] | o 8MB @40MB  (needs 48MB ws)

typedef __bf16 bf16;
typedef bf16 bf16x8 __attribute__((ext_vector_type(8)));
typedef bf16 bf16x4 __attribute__((ext_vector_type(4)));
typedef short s16x8 __attribute__((ext_vector_type(8)));
typedef float f32x4 __attribute__((ext_vector_type(4)));

#define MFMA32(a, b, c) __builtin_amdgcn_mfma_f32_16x16x32_bf16(a, b, c, 0, 0, 0)

// async global->LDS, 16B per lane; LDS dst must be wave-uniform base + lane*16
#define GLL(g, l) __builtin_amdgcn_global_load_lds(                              \
    (const __attribute__((address_space(1))) void*)(const void*)(g),             \
    (__attribute__((address_space(3))) void*)(void*)(l), 16, 0, 0)

union pk4 { bf16x4 h; unsigned int d[2]; };
union v8s { s16x8 s; bf16x8 v; };

// ---------------------------------------------------------------------------
// Kernel 0: fp32 -> bf16 conversion of x and the four weight matrices.
// ---------------------------------------------------------------------------
__global__ __launch_bounds__(256)
void cvt_bf16(const float* __restrict__ x,  const float* __restrict__ Wq,
              const float* __restrict__ Wk, const float* __restrict__ Wv,
              const float* __restrict__ Wo,
              bf16* __restrict__ xb, bf16* __restrict__ wqb, bf16* __restrict__ wkb,
              bf16* __restrict__ wvb, bf16* __restrict__ wob)
{
    const int idx = blockIdx.x * 256 + threadIdx.x;   // float4 index
    const float* src; bf16* dst; int off;
    if (idx < 1048576) { src = x; dst = xb; off = idx; }
    else {
        const int r = idx - 1048576;
        const int seg = r >> 18;          // 0..3  (262144 float4 per W)
        off = r & 262143;
        src = (seg == 0) ? Wq : (seg == 1) ? Wk : (seg == 2) ? Wv : Wo;
        dst = (seg == 0) ? wqb : (seg == 1) ? wkb : (seg == 2) ? wvb : wob;
    }
    const float4 v = ((const float4*)src)[off];
    bf16x4 o = {(bf16)v.x, (bf16)v.y, (bf16)v.z, (bf16)v.w};
    *(bf16x4*)(dst + (size_t)off * 4) = o;
}

// ---------------------------------------------------------------------------
// Kernel 1: fused QKV projection.  grid (32 Mtiles, 8 Ntiles, 3), 256 thr.
// BK=64, GLL staging with XOR swizzle: phys col p of row R holds
// k = p ^ ((R&7)*8)  ->  frag reads conflict-reduced.
// ---------------------------------------------------------------------------
__global__ __launch_bounds__(256, 3)
void qkv_gemm(const bf16* __restrict__ xb,
              const bf16* __restrict__ wqb, const float* __restrict__ bq,
              const bf16* __restrict__ wkb, const float* __restrict__ bk,
              const bf16* __restrict__ wvb, const float* __restrict__ bv,
              bf16* __restrict__ q_ws, bf16* __restrict__ k_ws, bf16* __restrict__ v_ws)
{
    const int z = blockIdx.z;
    const bf16*  W    = (z == 0) ? wqb : (z == 1) ? wkb : wvb;
    const float* bias = (z == 0) ? bq  : (z == 1) ? bk  : bv;

    __shared__ bf16 As[128][64];   // unpadded (GLL); swizzled columns
    __shared__ bf16 Bs[128][64];
    __shared__ char ebuf[17408];   // epilogue: Et[128][68] bf16 OR Vt[64][132] bf16
    bf16 (*Et)[68]  = (bf16(*)[68])ebuf;
    bf16 (*Vt)[132] = (bf16(*)[132])ebuf;

    const int m0 = blockIdx.x * 128;
    const int n0 = blockIdx.y * 128;
    const int t    = threadIdx.x;
    const int wave = t >> 6;
    const int lane = t & 63;
    const int lr   = lane & 15;
    const int quad = lane >> 4;
    const int wm = (wave & 1) * 64;
    const int wn = (wave >> 1) * 64;

    const int srow8 = lane >> 3;
    const int pcol  = (lane & 7) * 8;
    const int gcol  = ((lane & 7) ^ (lane >> 3)) * 8;   // swizzled global col
    const bf16* gaU[4]; const bf16* gbU[4]; bf16* laU[4]; bf16* lbU[4];
    #pragma unroll
    for (int u = 0; u < 4; u++) {
        const int row = wave * 32 + u * 8 + srow8;
        gaU[u] = xb + (size_t)(m0 + row) * 1024 + gcol;
        gbU[u] = W  + (size_t)(n0 + row) * 1024 + gcol;
        laU[u] = &As[row][pcol];
        lbU[u] = &Bs[row][pcol];
    }
    const int swA = (lr & 7) * 8;   // frag read swizzle for row wm+i*16+lr

    f32x4 acc[4][4] = {};

    for (int k0 = 0; k0 < 1024; k0 += 64) {
        #pragma unroll
        for (int u = 0; u < 4; u++) {
            GLL(gaU[u] + k0, laU[u]);
            GLL(gbU[u] + k0, lbU[u]);
        }
        __syncthreads();

        bf16x8 af[4][2], bfr[4][2];
        #pragma unroll
        for (int i = 0; i < 4; i++)
            #pragma unroll
            for (int kc = 0; kc < 2; kc++)
                af[i][kc] = *(const bf16x8*)&As[wm + i*16 + lr][(kc*32 + quad*8) ^ swA];
        #pragma unroll
        for (int j = 0; j < 4; j++)
            #pragma unroll
            for (int kc = 0; kc < 2; kc++)
                bfr[j][kc] = *(const bf16x8*)&Bs[wn + j*16 + lr][(kc*32 + quad*8) ^ swA];
        #pragma unroll
        for (int kc = 0; kc < 2; kc++)
            #pragma unroll
            for (int i = 0; i < 4; i++)
                #pragma unroll
                for (int j = 0; j < 4; j++)
                    acc[i][j] = MFMA32(af[i][kc], bfr[j][kc], acc[i][j]);
        __syncthreads();
    }

    const int bi = m0 >> 11, si0 = m0 & 2047;
    if (z < 2) {
        // q (pre-scaled 0.125) / k -> [b,h,s,dh] via LDS transpose
        bf16* hw = (z == 0) ? q_ws : k_ws;
        const float sc = (z == 0) ? 0.125f : 1.0f;
        #pragma unroll
        for (int ph = 0; ph < 2; ph++) {
            if ((wave >> 1) == ph) {
                #pragma unroll
                for (int j = 0; j < 4; j++) {
                    const float bb = bias[n0 + ph * 64 + j * 16 + lr];
                    #pragma unroll
                    for (int i = 0; i < 4; i++)
                        #pragma unroll
                        for (int r = 0; r < 4; r++)
                            Et[wm + i*16 + quad*4 + r][j*16 + lr] =
                                (bf16)((acc[i][j][r] + bb) * sc);
                }
            }
            __syncthreads();
            const int hh = (n0 >> 6) + ph;
            bf16* dst = hw + (((size_t)bi * 16 + hh) * 2048 + si0) * 64;
            const int row = t >> 1, cc = (t & 1) * 32;
            #pragma unroll
            for (int e = 0; e < 4; e++)
                *(bf16x8*)(dst + (size_t)row * 64 + cc + e * 8) =
                    *(const bf16x8*)&Et[row][cc + e * 8];
            __syncthreads();
        }
    } else {
        // v -> [b,h,dh,s] (transposed) via LDS
        #pragma unroll
        for (int ph = 0; ph < 2; ph++) {
            if ((wave >> 1) == ph) {
                #pragma unroll
                for (int j = 0; j < 4; j++) {
                    const float bb = bias[n0 + ph * 64 + j * 16 + lr];
                    #pragma unroll
                    for (int i = 0; i < 4; i++)
                        #pragma unroll
                        for (int r = 0; r < 4; r++)
                            Vt[j * 16 + lr][wm + i * 16 + quad * 4 + r] =
                                (bf16)(acc[i][j][r] + bb);
                }
            }
            __syncthreads();
            const int c  = t >> 2;             // local feature 0..63
            const int sc_ = (t & 3) * 32;
            const int col = n0 + ph * 64 + c;
            const int h = col >> 6, dh = col & 63;
            bf16* dst = v_ws + (((size_t)bi * 16 + h) * 64 + dh) * 2048 + si0 + sc_;
            #pragma unroll
            for (int e = 0; e < 4; e++)
                *(bf16x8*)(dst + e * 8) = *(const bf16x8*)&Vt[c][sc_ + e * 8];
            __syncthreads();
        }
    }
}

// ---------------------------------------------------------------------------
// Kernel 2: flash attention, fully transposed.  grid (32 q-tiles, 32 b*h).
// S^T = K.Q^T (C: key=quad*4+r, qrow=lr).  PV on MFMA32 only: K=32 P^T
// B-fragments built in-register via 8 shfl + 4 selects per 32-key chunk.
// l-sum via ones-MFMA32 on the same fragments (no MFMA16 anywhere).
// LDS: Ks 18KB + Vs 17KB = 35KB -> 4 blocks/CU.
// ---------------------------------------------------------------------------
__global__ __launch_bounds__(256, 4)
void attn(const bf16* __restrict__ q_ws, const bf16* __restrict__ k_ws,
          const bf16* __restrict__ v_ws, bf16* __restrict__ o_ws)
{
    const int qt = blockIdx.x;
    const int bh = blockIdx.y;           // b*16+h
    const int b_ = bh >> 4, h = bh & 15;

    const bf16* qbase = q_ws + (size_t)bh * 2048 * 64;
    const bf16* kbase = k_ws + (size_t)bh * 2048 * 64;
    const bf16* vbase = v_ws + (size_t)bh * 64 * 2048;  // [64][2048] V^T

    __shared__ bf16 Ks[128][72];     // [key][feat]
    __shared__ bf16 Vs[64][136];     // [feat][key]

    const int t    = threadIdx.x;
    const int wave = t >> 6;
    const int lane = t & 63;
    const int lr   = lane & 15;
    const int quad = lane >> 4;

    // Q fragments (pre-scaled by 0.125): B-operand of QK^T, n=qrow=lr
    bf16x8 aq[2];
    #pragma unroll
    for (int kc = 0; kc < 2; kc++)
        aq[kc] = *(const bf16x8*)(qbase +
            (size_t)(qt*64 + wave*16 + lr) * 64 + kc*32 + quad*8);

    float m_i = -1e30f, l_i = 0.f;       // stats for qrow = lr (per-lane)
    f32x4 o_accT[4] = {};                // O^T: rows feat, cols qrow=lr
    const float C = 1.44269504f;         // log2(e)
    v8s ones;
    ones.s = (s16x8){0x3F80, 0x3F80, 0x3F80, 0x3F80,
                     0x3F80, 0x3F80, 0x3F80, 0x3F80};   // bf16 1.0 x8

    // prefetch tile 0 into registers
    bf16x8 kreg[4], vreg[4];
    #pragma unroll
    for (int u = 0; u < 4; u++) {
        const int c = t + u * 256;
        kreg[u] = *(const bf16x8*)(kbase + (size_t)c * 8);
        vreg[u] = *(const bf16x8*)(vbase + (size_t)(c >> 4) * 2048 + (c & 15) * 8);
    }

    for (int kt = 0; kt < 16; kt++) {
        __syncthreads();     // previous tile's LDS reads done
        #pragma unroll
        for (int u = 0; u < 4; u++) {
            const int c = t + u * 256;
            *(bf16x8*)&Ks[c >> 3][(c & 7) * 8]  = kreg[u];
            *(bf16x8*)&Vs[c >> 4][(c & 15) * 8] = vreg[u];
        }
        __syncthreads();
        if (kt < 15) {
            #pragma unroll
            for (int u = 0; u < 4; u++) {
                const int c = t + u * 256;
                kreg[u] = *(const bf16x8*)(kbase + (size_t)(kt+1) * 8192 + c * 8);
                vreg[u] = *(const bf16x8*)(vbase + (size_t)(c >> 4) * 2048
                                           + (kt+1) * 128 + (c & 15) * 8);
            }
        }

        // S^T: 8 key-frags x 16 qrows
        f32x4 sacc[8];
        #pragma unroll
        for (int j = 0; j < 8; j++) {
            bf16x8 kf0 = *(const bf16x8*)&Ks[j*16 + lr][quad*8];
            bf16x8 kf1 = *(const bf16x8*)&Ks[j*16 + lr][32 + quad*8];
            f32x4 a = {0.f, 0.f, 0.f, 0.f};
            a = MFMA32(kf0, aq[0], a);
            a = MFMA32(kf1, aq[1], a);
            sacc[j] = a;
        }

        // online softmax max for qrow = lr (lane holds 32 of 128 keys)
        float m = -1e30f;
        #pragma unroll
        for (int j = 0; j < 8; j++)
            #pragma unroll
            for (int r = 0; r < 4; r++) m = fmaxf(m, sacc[j][r]);
        m = fmaxf(m, __shfl_xor(m, 16));
        m = fmaxf(m, __shfl_xor(m, 32));
        const float nm = fmaxf(m_i, m);
        const float al = exp2f((m_i - nm) * C);
        m_i = nm;
        const float nmc = nm * C;
        // rescale O^T: alpha is a per-lane scalar (cols are qrow=lr)
        #pragma unroll
        for (int n = 0; n < 4; n++)
            #pragma unroll
            for (int r = 0; r < 4; r++) o_accT[n][r] *= al;

        // exp + pack (keys j*16+quad*4+r at qrow=lr -> two dwords per j)
        unsigned int p0[8], p1[8];
        #pragma unroll
        for (int j = 0; j < 8; j++) {
            pk4 pf;
            pf.h = bf16x4{(bf16)exp2f(fmaf(sacc[j][0], C, -nmc)),
                          (bf16)exp2f(fmaf(sacc[j][1], C, -nmc)),
                          (bf16)exp2f(fmaf(sacc[j][2], C, -nmc)),
                          (bf16)exp2f(fmaf(sacc[j][3], C, -nmc))};
            p0[j] = pf.d[0]; p1[j] = pf.d[1];
        }

        // Build K=32 P^T B-frags via shuffles; PV + l-sum on MFMA32.
        // Lane (lr,quad) needs keys c*32+quad*8+{0..7} @ qrow=lr:
        //   j0 = 2c + (quad>>1); halves from lanes 32*(quad&1)+lr (+16).
        const int srcA = lr + 32 * (quad & 1);
        const int srcB = srcA + 16;
        const bool hi = (quad >> 1) != 0;
        f32x4 lacc = {0.f, 0.f, 0.f, 0.f};
        #pragma unroll
        for (int c = 0; c < 4; c++) {
            unsigned int a0 = __shfl(p0[2*c], srcA), a1 = __shfl(p0[2*c+1], srcA);
            unsigned int b0 = __shfl(p1[2*c], srcA), b1 = __shfl(p1[2*c+1], srcA);
            unsigned int c0 = __shfl(p0[2*c], srcB), c1 = __shfl(p0[2*c+1], srcB);
            unsigned int d0 = __shfl(p1[2*c], srcB), d1 = __shfl(p1[2*c+1], srcB);
            unsigned int fr[4];
            fr[0] = hi ? a1 : a0;
            fr[1] = hi ? b1 : b0;
            fr[2] = hi ? c1 : c0;
            fr[3] = hi ? d1 : d0;
            bf16x8 pf8 = *(bf16x8*)fr;
            #pragma unroll
            for (int fb = 0; fb < 4; fb++) {
                bf16x8 vf8 = *(const bf16x8*)&Vs[fb*16 + lr][c*32 + quad*8];
                o_accT[fb] = MFMA32(vf8, pf8, o_accT[fb]);
            }
            lacc = MFMA32(ones.v, pf8, lacc);
        }
        l_i = l_i * al + lacc[0];
    }

    // epilogue: divide, transpose through reused Ks LDS, coalesced stores
    __syncthreads();                      // all waves done reading Ks/Vs
    bf16 (*OsE)[68] = (bf16(*)[68])&Ks[0][0];    // 64 x 68 bf16 = 8.7KB
    const float inv = 1.0f / l_i;
    const int sil = wave * 16 + lr;       // local si 0..63
    #pragma unroll
    for (int fb = 0; fb < 4; fb++)
        #pragma unroll
        for (int r = 0; r < 4; r++)
            OsE[sil][fb*16 + quad*4 + r] = (bf16)(o_accT[fb][r] * inv);
    __syncthreads();
    const int row = t >> 2, seg = (t & 3) * 16;
    bf16* dst = o_ws + ((size_t)b_ * 2048 + qt*64 + row) * 1024 + h*64 + seg;
    *(bf16x8*)(dst)     = *(const bf16x8*)&OsE[row][seg];
    *(bf16x8*)(dst + 8) = *(const bf16x8*)&OsE[row][seg + 8];
}

// ---------------------------------------------------------------------------
// Kernel 3: output projection.  64x128 tiles, grid (64,8), BK=64 + swizzle.
// ---------------------------------------------------------------------------
__global__ __launch_bounds__(256, 3)
void out_gemm(const bf16* __restrict__ o_ws,
              const bf16* __restrict__ wob, const float* __restrict__ bo,
              float* __restrict__ out)
{
    __shared__ bf16 As[64][64];
    __shared__ bf16 Bs[128][64];
    __shared__ float Ot[64][68];   // 17.4KB epilogue staging

    const int m0 = blockIdx.x * 64;
    const int n0 = blockIdx.y * 128;
    const int t    = threadIdx.x;
    const int wave = t >> 6;
    const int lane = t & 63;
    const int lr   = lane & 15;
    const int quad = lane >> 4;
    const int wm = (wave & 1) * 32;
    const int wn = (wave >> 1) * 64;

    const int srow8 = lane >> 3;
    const int pcol  = (lane & 7) * 8;
    const int gcol  = ((lane & 7) ^ (lane >> 3)) * 8;
    const bf16* gaU[2]; bf16* laU[2];
    #pragma unroll
    for (int u = 0; u < 2; u++) {
        const int row = wave * 16 + u * 8 + srow8;
        gaU[u] = o_ws + (size_t)(m0 + row) * 1024 + gcol;
        laU[u] = &As[row][pcol];
    }
    const bf16* gbU[4]; bf16* lbU[4];
    #pragma unroll
    for (int u = 0; u < 4; u++) {
        const int row = wave * 32 + u * 8 + srow8;
        gbU[u] = wob + (size_t)(n0 + row) * 1024 + gcol;
        lbU[u] = &Bs[row][pcol];
    }
    const int swA = (lr & 7) * 8;

    f32x4 acc[2][4] = {};

    for (int k0 = 0; k0 < 1024; k0 += 64) {
        #pragma unroll
        for (int u = 0; u < 2; u++) GLL(gaU[u] + k0, laU[u]);
        #pragma unroll
        for (int u = 0; u < 4; u++) GLL(gbU[u] + k0, lbU[u]);
        __syncthreads();

        bf16x8 af[2][2], bfr[4][2];
        #pragma unroll
        for (int i = 0; i < 2; i++)
            #pragma unroll
            for (int kc = 0; kc < 2; kc++)
                af[i][kc] = *(const bf16x8*)&As[wm + i*16 + lr][(kc*32 + quad*8) ^ swA];
        #pragma unroll
        for (int j = 0; j < 4; j++)
            #pragma unroll
            for (int kc = 0; kc < 2; kc++)
                bfr[j][kc] = *(const bf16x8*)&Bs[wn + j*16 + lr][(kc*32 + quad*8) ^ swA];
        #pragma unroll
        for (int kc = 0; kc < 2; kc++)
            #pragma unroll
            for (int i = 0; i < 2; i++)
                #pragma unroll
                for (int j = 0; j < 4; j++)
                    acc[i][j] = MFMA32(af[i][kc], bfr[j][kc], acc[i][j]);
        __syncthreads();
    }

    #pragma unroll
    for (int ph = 0; ph < 2; ph++) {
        if ((wave >> 1) == ph) {
            #pragma unroll
            for (int j = 0; j < 4; j++) {
                const float bb = bo[n0 + ph * 64 + j * 16 + lr];
                #pragma unroll
                for (int i = 0; i < 2; i++)
                    #pragma unroll
                    for (int r = 0; r < 4; r++)
                        Ot[wm + i*16 + quad*4 + r][j*16 + lr] = acc[i][j][r] + bb;
            }
        }
        __syncthreads();
        const int row = t >> 2, seg = (t & 3) * 16;
        float* dst = out + (size_t)(m0 + row) * 1024 + n0 + ph * 64 + seg;
        #pragma unroll
        for (int e = 0; e < 4; e++)
            *(float4*)(dst + e * 4) = *(const float4*)&Ot[row][seg + e * 4];
        __syncthreads();
    }
}

extern "C" void kernel_launch(void* const* d_in, const int* in_sizes, int n_in,
                              void* d_out, int out_size, void* d_ws, size_t ws_size,
                              hipStream_t stream) {
    (void)in_sizes; (void)n_in; (void)out_size; (void)ws_size;
    const float* x  = (const float*)d_in[0];
    const float* Wq = (const float*)d_in[1];
    const float* bq = (const float*)d_in[2];
    const float* Wk = (const float*)d_in[3];
    const float* bk = (const float*)d_in[4];
    const float* Wv = (const float*)d_in[5];
    const float* bv = (const float*)d_in[6];
    const float* Wo = (const float*)d_in[7];
    const float* bo = (const float*)d_in[8];
    float* out = (float*)d_out;

    char* ws = (char*)d_ws;
    const size_t MB = 1024 * 1024;
    bf16* xb   = (bf16*)(ws);
    bf16* wqb  = (bf16*)(ws + 8 * MB);
    bf16* wkb  = (bf16*)(ws + 10 * MB);
    bf16* wvb  = (bf16*)(ws + 12 * MB);
    bf16* wob  = (bf16*)(ws + 14 * MB);
    bf16* q_ws = (bf16*)(ws + 16 * MB);
    bf16* k_ws = (bf16*)(ws + 24 * MB);
    bf16* v_ws = (bf16*)(ws + 32 * MB);
    bf16* o_ws = (bf16*)(ws + 40 * MB);

    hipLaunchKernelGGL(cvt_bf16, dim3(8192), dim3(256), 0, stream,
                       x, Wq, Wk, Wv, Wo, xb, wqb, wkb, wvb, wob);
    hipLaunchKernelGGL(qkv_gemm, dim3(32, 8, 3), dim3(256), 0, stream,
                       xb, wqb, bq, wkb, bk, wvb, bv, q_ws, k_ws, v_ws);
    hipLaunchKernelGGL(attn, dim3(32, 32), dim3(256), 0, stream,
                       q_ws, k_ws, v_ws, o_ws);
    hipLaunchKernelGGL(out_gemm, dim3(64, 8), dim3(256), 0, stream,
                       o_ws, wob, bo, out);
}

// Round 8
// 226.522 us; speedup vs baseline: 1.0496x; 1.0496x over previous
//
#include <hip/hip_runtime.h>

// MHA: B=2 S=2048 D=1024 H=16 DH=64.  All GEMMs bf16 MFMA, fp32 acc.
// R8: attn reverted to the R5 per-wave algorithm (direct-MFMA16 PV ~4.3cyc,
//     VALU l-sum; R7's shuffle PV was latency-bound) and widened to 512-thread
//     blocks (128 Q-rows, 8 waves) -> 16 waves/CU for stall hiding.
//     GEMM kernels unchanged from R6 (BK=64 + XOR swizzle).
// ws: xb 8MB @0 | wq/wk/wv/wo bf16 2MB each @8/10/12/14MB | q 8MB @16MB |
//     k 8MB @24MB | v^T 8MB @32MB [b,h,dh,s] | o 8MB @40MB  (needs 48MB ws)

typedef __bf16 bf16;
typedef bf16 bf16x8 __attribute__((ext_vector_type(8)));
typedef bf16 bf16x4 __attribute__((ext_vector_type(4)));
typedef short s16x4 __attribute__((ext_vector_type(4)));
typedef float f32x4 __attribute__((ext_vector_type(4)));

#define MFMA32(a, b, c) __builtin_amdgcn_mfma_f32_16x16x32_bf16(a, b, c, 0, 0, 0)

#if __has_builtin(__builtin_amdgcn_mfma_f32_16x16x16bf16_1k)
#define HAVE_MFMA16 1
#define MFMA16(a, b, c) __builtin_amdgcn_mfma_f32_16x16x16bf16_1k(a, b, c, 0, 0, 0)
#else
#define HAVE_MFMA16 0
#endif

// async global->LDS, 16B per lane; LDS dst must be wave-uniform base + lane*16
#define GLL(g, l) __builtin_amdgcn_global_load_lds(                              \
    (const __attribute__((address_space(1))) void*)(const void*)(g),             \
    (__attribute__((address_space(3))) void*)(void*)(l), 16, 0, 0)

union pk4 { bf16x4 h; s16x4 s; unsigned int d[2]; };

// ---------------------------------------------------------------------------
// Kernel 0: fp32 -> bf16 conversion of x and the four weight matrices.
// ---------------------------------------------------------------------------
__global__ __launch_bounds__(256)
void cvt_bf16(const float* __restrict__ x,  const float* __restrict__ Wq,
              const float* __restrict__ Wk, const float* __restrict__ Wv,
              const float* __restrict__ Wo,
              bf16* __restrict__ xb, bf16* __restrict__ wqb, bf16* __restrict__ wkb,
              bf16* __restrict__ wvb, bf16* __restrict__ wob)
{
    const int idx = blockIdx.x * 256 + threadIdx.x;   // float4 index
    const float* src; bf16* dst; int off;
    if (idx < 1048576) { src = x; dst = xb; off = idx; }
    else {
        const int r = idx - 1048576;
        const int seg = r >> 18;          // 0..3  (262144 float4 per W)
        off = r & 262143;
        src = (seg == 0) ? Wq : (seg == 1) ? Wk : (seg == 2) ? Wv : Wo;
        dst = (seg == 0) ? wqb : (seg == 1) ? wkb : (seg == 2) ? wvb : wob;
    }
    const float4 v = ((const float4*)src)[off];
    bf16x4 o = {(bf16)v.x, (bf16)v.y, (bf16)v.z, (bf16)v.w};
    *(bf16x4*)(dst + (size_t)off * 4) = o;
}

// ---------------------------------------------------------------------------
// Kernel 1: fused QKV projection.  grid (32 Mtiles, 8 Ntiles, 3), 256 thr.
// BK=64, GLL staging with XOR swizzle: phys col p of row R holds
// k = p ^ ((R&7)*8)  ->  frag reads conflict-reduced.
// ---------------------------------------------------------------------------
__global__ __launch_bounds__(256, 3)
void qkv_gemm(const bf16* __restrict__ xb,
              const bf16* __restrict__ wqb, const float* __restrict__ bq,
              const bf16* __restrict__ wkb, const float* __restrict__ bk,
              const bf16* __restrict__ wvb, const float* __restrict__ bv,
              bf16* __restrict__ q_ws, bf16* __restrict__ k_ws, bf16* __restrict__ v_ws)
{
    const int z = blockIdx.z;
    const bf16*  W    = (z == 0) ? wqb : (z == 1) ? wkb : wvb;
    const float* bias = (z == 0) ? bq  : (z == 1) ? bk  : bv;

    __shared__ bf16 As[128][64];   // unpadded (GLL); swizzled columns
    __shared__ bf16 Bs[128][64];
    __shared__ char ebuf[17408];   // epilogue: Et[128][68] bf16 OR Vt[64][132] bf16
    bf16 (*Et)[68]  = (bf16(*)[68])ebuf;
    bf16 (*Vt)[132] = (bf16(*)[132])ebuf;

    const int m0 = blockIdx.x * 128;
    const int n0 = blockIdx.y * 128;
    const int t    = threadIdx.x;
    const int wave = t >> 6;
    const int lane = t & 63;
    const int lr   = lane & 15;
    const int quad = lane >> 4;
    const int wm = (wave & 1) * 64;
    const int wn = (wave >> 1) * 64;

    const int srow8 = lane >> 3;
    const int pcol  = (lane & 7) * 8;
    const int gcol  = ((lane & 7) ^ (lane >> 3)) * 8;   // swizzled global col
    const bf16* gaU[4]; const bf16* gbU[4]; bf16* laU[4]; bf16* lbU[4];
    #pragma unroll
    for (int u = 0; u < 4; u++) {
        const int row = wave * 32 + u * 8 + srow8;
        gaU[u] = xb + (size_t)(m0 + row) * 1024 + gcol;
        gbU[u] = W  + (size_t)(n0 + row) * 1024 + gcol;
        laU[u] = &As[row][pcol];
        lbU[u] = &Bs[row][pcol];
    }
    const int swA = (lr & 7) * 8;   // frag read swizzle for row wm+i*16+lr

    f32x4 acc[4][4] = {};

    for (int k0 = 0; k0 < 1024; k0 += 64) {
        #pragma unroll
        for (int u = 0; u < 4; u++) {
            GLL(gaU[u] + k0, laU[u]);
            GLL(gbU[u] + k0, lbU[u]);
        }
        __syncthreads();

        bf16x8 af[4][2], bfr[4][2];
        #pragma unroll
        for (int i = 0; i < 4; i++)
            #pragma unroll
            for (int kc = 0; kc < 2; kc++)
                af[i][kc] = *(const bf16x8*)&As[wm + i*16 + lr][(kc*32 + quad*8) ^ swA];
        #pragma unroll
        for (int j = 0; j < 4; j++)
            #pragma unroll
            for (int kc = 0; kc < 2; kc++)
                bfr[j][kc] = *(const bf16x8*)&Bs[wn + j*16 + lr][(kc*32 + quad*8) ^ swA];
        #pragma unroll
        for (int kc = 0; kc < 2; kc++)
            #pragma unroll
            for (int i = 0; i < 4; i++)
                #pragma unroll
                for (int j = 0; j < 4; j++)
                    acc[i][j] = MFMA32(af[i][kc], bfr[j][kc], acc[i][j]);
        __syncthreads();
    }

    const int bi = m0 >> 11, si0 = m0 & 2047;
    if (z < 2) {
        // q (pre-scaled 0.125) / k -> [b,h,s,dh] via LDS transpose
        bf16* hw = (z == 0) ? q_ws : k_ws;
        const float sc = (z == 0) ? 0.125f : 1.0f;
        #pragma unroll
        for (int ph = 0; ph < 2; ph++) {
            if ((wave >> 1) == ph) {
                #pragma unroll
                for (int j = 0; j < 4; j++) {
                    const float bb = bias[n0 + ph * 64 + j * 16 + lr];
                    #pragma unroll
                    for (int i = 0; i < 4; i++)
                        #pragma unroll
                        for (int r = 0; r < 4; r++)
                            Et[wm + i*16 + quad*4 + r][j*16 + lr] =
                                (bf16)((acc[i][j][r] + bb) * sc);
                }
            }
            __syncthreads();
            const int hh = (n0 >> 6) + ph;
            bf16* dst = hw + (((size_t)bi * 16 + hh) * 2048 + si0) * 64;
            const int row = t >> 1, cc = (t & 1) * 32;
            #pragma unroll
            for (int e = 0; e < 4; e++)
                *(bf16x8*)(dst + (size_t)row * 64 + cc + e * 8) =
                    *(const bf16x8*)&Et[row][cc + e * 8];
            __syncthreads();
        }
    } else {
        // v -> [b,h,dh,s] (transposed) via LDS
        #pragma unroll
        for (int ph = 0; ph < 2; ph++) {
            if ((wave >> 1) == ph) {
                #pragma unroll
                for (int j = 0; j < 4; j++) {
                    const float bb = bias[n0 + ph * 64 + j * 16 + lr];
                    #pragma unroll
                    for (int i = 0; i < 4; i++)
                        #pragma unroll
                        for (int r = 0; r < 4; r++)
                            Vt[j * 16 + lr][wm + i * 16 + quad * 4 + r] =
                                (bf16)(acc[i][j][r] + bb);
                }
            }
            __syncthreads();
            const int c  = t >> 2;             // local feature 0..63
            const int sc_ = (t & 3) * 32;
            const int col = n0 + ph * 64 + c;
            const int h = col >> 6, dh = col & 63;
            bf16* dst = v_ws + (((size_t)bi * 16 + h) * 64 + dh) * 2048 + si0 + sc_;
            #pragma unroll
            for (int e = 0; e < 4; e++)
                *(bf16x8*)(dst + e * 8) = *(const bf16x8*)&Vt[c][sc_ + e * 8];
            __syncthreads();
        }
    }
}

// ---------------------------------------------------------------------------
// Kernel 2: flash attention.  512 threads (8 waves), grid (16 q-tiles, 32 bh).
// Block = 128 Q rows; wave owns 16 (qrow=lane&15).  S^T = K.Q^T; softmaxed
// sacc is directly the B-operand of the 16x16x16 PV MFMA (O^T = V^T.P^T);
// per-row stats per-lane.  LDS: Ks 18KB + Vs 17KB = 35KB.
// ---------------------------------------------------------------------------
__global__ __launch_bounds__(512, 4)
void attn(const bf16* __restrict__ q_ws, const bf16* __restrict__ k_ws,
          const bf16* __restrict__ v_ws, bf16* __restrict__ o_ws)
{
    const int qt = blockIdx.x;
    const int bh = blockIdx.y;           // b*16+h
    const int b_ = bh >> 4, h = bh & 15;

    const bf16* qbase = q_ws + (size_t)bh * 2048 * 64;
    const bf16* kbase = k_ws + (size_t)bh * 2048 * 64;
    const bf16* vbase = v_ws + (size_t)bh * 64 * 2048;  // [64][2048] V^T

    __shared__ bf16 Ks[128][72];     // [key][feat]
    __shared__ bf16 Vs[64][136];     // [feat][key]

    const int t    = threadIdx.x;
    const int wave = t >> 6;
    const int lane = t & 63;
    const int lr   = lane & 15;
    const int quad = lane >> 4;

    // Q fragments (pre-scaled by 0.125): B-operand of QK^T, n=qrow=lr
    bf16x8 aq[2];
    #pragma unroll
    for (int kc = 0; kc < 2; kc++)
        aq[kc] = *(const bf16x8*)(qbase +
            (size_t)(qt*128 + wave*16 + lr) * 64 + kc*32 + quad*8);

    float m_i = -1e30f, l_i = 0.f;       // stats for qrow = lr (per-lane)
    f32x4 o_accT[4] = {};                // O^T: rows feat, cols qrow=lr
    const float C = 1.44269504f;         // log2(e)

    // prefetch tile 0 into registers (512 threads -> 2 chunks each)
    bf16x8 kreg[2], vreg[2];
    #pragma unroll
    for (int u = 0; u < 2; u++) {
        const int c = t + u * 512;
        kreg[u] = *(const bf16x8*)(kbase + (size_t)c * 8);
        vreg[u] = *(const bf16x8*)(vbase + (size_t)(c >> 4) * 2048 + (c & 15) * 8);
    }

    for (int kt = 0; kt < 16; kt++) {
        __syncthreads();     // previous tile's LDS reads done
        #pragma unroll
        for (int u = 0; u < 2; u++) {
            const int c = t + u * 512;
            *(bf16x8*)&Ks[c >> 3][(c & 7) * 8]  = kreg[u];
            *(bf16x8*)&Vs[c >> 4][(c & 15) * 8] = vreg[u];
        }
        __syncthreads();
        if (kt < 15) {
            #pragma unroll
            for (int u = 0; u < 2; u++) {
                const int c = t + u * 512;
                kreg[u] = *(const bf16x8*)(kbase + (size_t)(kt+1) * 8192 + c * 8);
                vreg[u] = *(const bf16x8*)(vbase + (size_t)(c >> 4) * 2048
                                           + (kt+1) * 128 + (c & 15) * 8);
            }
        }

        // S^T: 8 key-frags x 16 qrows
        f32x4 sacc[8];
        #pragma unroll
        for (int j = 0; j < 8; j++) {
            bf16x8 kf0 = *(const bf16x8*)&Ks[j*16 + lr][quad*8];
            bf16x8 kf1 = *(const bf16x8*)&Ks[j*16 + lr][32 + quad*8];
            f32x4 a = {0.f, 0.f, 0.f, 0.f};
            a = MFMA32(kf0, aq[0], a);
            a = MFMA32(kf1, aq[1], a);
            sacc[j] = a;
        }

        // online softmax for qrow = lr (lane holds 32 of 128 keys)
        float m = -1e30f;
        #pragma unroll
        for (int j = 0; j < 8; j++)
            #pragma unroll
            for (int r = 0; r < 4; r++) m = fmaxf(m, sacc[j][r]);
        m = fmaxf(m, __shfl_xor(m, 16));
        m = fmaxf(m, __shfl_xor(m, 32));
        const float nm = fmaxf(m_i, m);
        const float al = exp2f((m_i - nm) * C);
        m_i = nm;
        const float nmc = nm * C;
        float rs = 0.f;
        #pragma unroll
        for (int j = 0; j < 8; j++)
            #pragma unroll
            for (int r = 0; r < 4; r++) {
                const float p = exp2f(fmaf(sacc[j][r], C, -nmc));
                sacc[j][r] = p;
                rs += p;
            }
        // rescale O^T: alpha is a per-lane scalar (cols are qrow=lr)
        #pragma unroll
        for (int n = 0; n < 4; n++)
            #pragma unroll
            for (int r = 0; r < 4; r++) o_accT[n][r] *= al;
        // l update (off the PV critical path)
        rs += __shfl_xor(rs, 16);
        rs += __shfl_xor(rs, 32);
        l_i = l_i * al + rs;

#if HAVE_MFMA16
        // O^T += V^T . P^T : A = V^T frag (8B from Vs), B = sacc directly
        #pragma unroll
        for (int j = 0; j < 8; j++) {
            pk4 pf;
            pf.h = bf16x4{(bf16)sacc[j][0], (bf16)sacc[j][1],
                          (bf16)sacc[j][2], (bf16)sacc[j][3]};
            #pragma unroll
            for (int fb = 0; fb < 4; fb++) {
                pk4 vf;
                *(unsigned long long*)vf.d =
                    *(const unsigned long long*)&Vs[fb*16 + lr][j*16 + quad*4];
                o_accT[fb] = MFMA16(vf.s, pf.s, o_accT[fb]);
            }
        }
#else
        // Fallback: build K=32 B-frags of P^T via shuffles, MFMA32 with A=V^T.
        unsigned int p0[8], p1[8];
        #pragma unroll
        for (int j = 0; j < 8; j++) {
            pk4 pf;
            pf.h = bf16x4{(bf16)sacc[j][0], (bf16)sacc[j][1],
                          (bf16)sacc[j][2], (bf16)sacc[j][3]};
            p0[j] = pf.d[0]; p1[j] = pf.d[1];
        }
        const int srcA = lr + 32 * (quad & 1);
        const int srcB = srcA + 16;
        const bool hi = (quad >> 1) != 0;
        #pragma unroll
        for (int c = 0; c < 4; c++) {
            unsigned int a0 = __shfl(p0[2*c], srcA), a1 = __shfl(p0[2*c+1], srcA);
            unsigned int b0 = __shfl(p1[2*c], srcA), b1 = __shfl(p1[2*c+1], srcA);
            unsigned int c0 = __shfl(p0[2*c], srcB), c1 = __shfl(p0[2*c+1], srcB);
            unsigned int d0 = __shfl(p1[2*c], srcB), d1 = __shfl(p1[2*c+1], srcB);
            unsigned int fr[4];
            fr[0] = hi ? a1 : a0;
            fr[1] = hi ? b1 : b0;
            fr[2] = hi ? c1 : c0;
            fr[3] = hi ? d1 : d0;
            bf16x8 pf8 = *(bf16x8*)fr;
            #pragma unroll
            for (int fb = 0; fb < 4; fb++) {
                bf16x8 vf8 = *(const bf16x8*)&Vs[fb*16 + lr][c*32 + quad*8];
                o_accT[fb] = MFMA32(vf8, pf8, o_accT[fb]);
            }
        }
#endif
    }

    // epilogue: divide, transpose through reused Ks LDS, coalesced stores
    __syncthreads();                      // all waves done reading Ks/Vs
    bf16 (*OsE)[68] = (bf16(*)[68])&Ks[0][0];    // 128 x 68 bf16 = 17.4KB
    const float inv = 1.0f / l_i;
    const int sil = wave * 16 + lr;       // local si 0..127
    #pragma unroll
    for (int fb = 0; fb < 4; fb++)
        #pragma unroll
        for (int r = 0; r < 4; r++)
            OsE[sil][fb*16 + quad*4 + r] = (bf16)(o_accT[fb][r] * inv);
    __syncthreads();
    const int row = t >> 2, seg = (t & 3) * 16;   // row 0..127
    bf16* dst = o_ws + ((size_t)b_ * 2048 + qt*128 + row) * 1024 + h*64 + seg;
    *(bf16x8*)(dst)     = *(const bf16x8*)&OsE[row][seg];
    *(bf16x8*)(dst + 8) = *(const bf16x8*)&OsE[row][seg + 8];
}

// ---------------------------------------------------------------------------
// Kernel 3: output projection.  64x128 tiles, grid (64,8), BK=64 + swizzle.
// ---------------------------------------------------------------------------
__global__ __launch_bounds__(256, 3)
void out_gemm(const bf16* __restrict__ o_ws,
              const bf16* __restrict__ wob, const float* __restrict__ bo,
              float* __restrict__ out)
{
    __shared__ bf16 As[64][64];
    __shared__ bf16 Bs[128][64];
    __shared__ float Ot[64][68];   // 17.4KB epilogue staging

    const int m0 = blockIdx.x * 64;
    const int n0 = blockIdx.y * 128;
    const int t    = threadIdx.x;
    const int wave = t >> 6;
    const int lane = t & 63;
    const int lr   = lane & 15;
    const int quad = lane >> 4;
    const int wm = (wave & 1) * 32;
    const int wn = (wave >> 1) * 64;

    const int srow8 = lane >> 3;
    const int pcol  = (lane & 7) * 8;
    const int gcol  = ((lane & 7) ^ (lane >> 3)) * 8;
    const bf16* gaU[2]; bf16* laU[2];
    #pragma unroll
    for (int u = 0; u < 2; u++) {
        const int row = wave * 16 + u * 8 + srow8;
        gaU[u] = o_ws + (size_t)(m0 + row) * 1024 + gcol;
        laU[u] = &As[row][pcol];
    }
    const bf16* gbU[4]; bf16* lbU[4];
    #pragma unroll
    for (int u = 0; u < 4; u++) {
        const int row = wave * 32 + u * 8 + srow8;
        gbU[u] = wob + (size_t)(n0 + row) * 1024 + gcol;
        lbU[u] = &Bs[row][pcol];
    }
    const int swA = (lr & 7) * 8;

    f32x4 acc[2][4] = {};

    for (int k0 = 0; k0 < 1024; k0 += 64) {
        #pragma unroll
        for (int u = 0; u < 2; u++) GLL(gaU[u] + k0, laU[u]);
        #pragma unroll
        for (int u = 0; u < 4; u++) GLL(gbU[u] + k0, lbU[u]);
        __syncthreads();

        bf16x8 af[2][2], bfr[4][2];
        #pragma unroll
        for (int i = 0; i < 2; i++)
            #pragma unroll
            for (int kc = 0; kc < 2; kc++)
                af[i][kc] = *(const bf16x8*)&As[wm + i*16 + lr][(kc*32 + quad*8) ^ swA];
        #pragma unroll
        for (int j = 0; j < 4; j++)
            #pragma unroll
            for (int kc = 0; kc < 2; kc++)
                bfr[j][kc] = *(const bf16x8*)&Bs[wn + j*16 + lr][(kc*32 + quad*8) ^ swA];
        #pragma unroll
        for (int kc = 0; kc < 2; kc++)
            #pragma unroll
            for (int i = 0; i < 2; i++)
                #pragma unroll
                for (int j = 0; j < 4; j++)
                    acc[i][j] = MFMA32(af[i][kc], bfr[j][kc], acc[i][j]);
        __syncthreads();
    }

    #pragma unroll
    for (int ph = 0; ph < 2; ph++) {
        if ((wave >> 1) == ph) {
            #pragma unroll
            for (int j = 0; j < 4; j++) {
                const float bb = bo[n0 + ph * 64 + j * 16 + lr];
                #pragma unroll
                for (int i = 0; i < 2; i++)
                    #pragma unroll
                    for (int r = 0; r < 4; r++)
                        Ot[wm + i*16 + quad*4 + r][j*16 + lr] = acc[i][j][r] + bb;
            }
        }
        __syncthreads();
        const int row = t >> 2, seg = (t & 3) * 16;
        float* dst = out + (size_t)(m0 + row) * 1024 + n0 + ph * 64 + seg;
        #pragma unroll
        for (int e = 0; e < 4; e++)
            *(float4*)(dst + e * 4) = *(const float4*)&Ot[row][seg + e * 4];
        __syncthreads();
    }
}

extern "C" void kernel_launch(void* const* d_in, const int* in_sizes, int n_in,
                              void* d_out, int out_size, void* d_ws, size_t ws_size,
                              hipStream_t stream) {
    (void)in_sizes; (void)n_in; (void)out_size; (void)ws_size;
    const float* x  = (const float*)d_in[0];
    const float* Wq = (const float*)d_in[1];
    const float* bq = (const float*)d_in[2];
    const float* Wk = (const float*)d_in[3];
    const float* bk = (const float*)d_in[4];
    const float* Wv = (const float*)d_in[5];
    const float* bv = (const float*)d_in[6];
    const float* Wo = (const float*)d_in[7];
    const float* bo = (const float*)d_in[8];
    float* out = (float*)d_out;

    char* ws = (char*)d_ws;
    const size_t MB = 1024 * 1024;
    bf16* xb   = (bf16*)(ws);
    bf16* wqb  = (bf16*)(ws + 8 * MB);
    bf16* wkb  = (bf16*)(ws + 10 * MB);
    bf16* wvb  = (bf16*)(ws + 12 * MB);
    bf16* wob  = (bf16*)(ws + 14 * MB);
    bf16* q_ws = (bf16*)(ws + 16 * MB);
    bf16* k_ws = (bf16*)(ws + 24 * MB);
    bf16* v_ws = (bf16*)(ws + 32 * MB);
    bf16* o_ws = (bf16*)(ws + 40 * MB);

    hipLaunchKernelGGL(cvt_bf16, dim3(8192), dim3(256), 0, stream,
                       x, Wq, Wk, Wv, Wo, xb, wqb, wkb, wvb, wob);
    hipLaunchKernelGGL(qkv_gemm, dim3(32, 8, 3), dim3(256), 0, stream,
                       xb, wqb, bq, wkb, bk, wvb, bv, q_ws, k_ws, v_ws);
    hipLaunchKernelGGL(attn, dim3(16, 32), dim3(512), 0, stream,
                       q_ws, k_ws, v_ws, o_ws);
    hipLaunchKernelGGL(out_gemm, dim3(64, 8), dim3(256), 0, stream,
                       o_ws, wob, bo, out);
}

// Round 9
// 212.653 us; speedup vs baseline: 1.1181x; 1.0652x over previous
//
#include <hip/hip_runtime.h>

// MHA: B=2 S=2048 D=1024 H=16 DH=64.  All GEMMs bf16 MFMA, fp32 acc.
// R9: attn only: (a) Vs stride 136->140 bf16 (70 dw) breaks the 4-way bank
//     conflict on PV ds_read_b64 (banks 2(3lr+quad)%32 -> <=2-way, free);
//     (b) grid swizzled to (32 bh, 16 qt) so all 16 q-tiles of one head land
//     on the same XCD (linear id % 8 == bh % 8) -> K/V L2 reuse.
//     GEMM kernels unchanged from R6/R8.
// ws: xb 8MB @0 | wq/wk/wv/wo bf16 2MB each @8/10/12/14MB | q 8MB @16MB |
//     k 8MB @24MB | v^T 8MB @32MB [b,h,dh,s] | o 8MB @40MB  (needs 48MB ws)

typedef __bf16 bf16;
typedef bf16 bf16x8 __attribute__((ext_vector_type(8)));
typedef bf16 bf16x4 __attribute__((ext_vector_type(4)));
typedef short s16x4 __attribute__((ext_vector_type(4)));
typedef float f32x4 __attribute__((ext_vector_type(4)));

#define MFMA32(a, b, c) __builtin_amdgcn_mfma_f32_16x16x32_bf16(a, b, c, 0, 0, 0)

#if __has_builtin(__builtin_amdgcn_mfma_f32_16x16x16bf16_1k)
#define HAVE_MFMA16 1
#define MFMA16(a, b, c) __builtin_amdgcn_mfma_f32_16x16x16bf16_1k(a, b, c, 0, 0, 0)
#else
#define HAVE_MFMA16 0
#endif

// async global->LDS, 16B per lane; LDS dst must be wave-uniform base + lane*16
#define GLL(g, l) __builtin_amdgcn_global_load_lds(                              \
    (const __attribute__((address_space(1))) void*)(const void*)(g),             \
    (__attribute__((address_space(3))) void*)(void*)(l), 16, 0, 0)

union pk4 { bf16x4 h; s16x4 s; unsigned int d[2]; };

// ---------------------------------------------------------------------------
// Kernel 0: fp32 -> bf16 conversion of x and the four weight matrices.
// ---------------------------------------------------------------------------
__global__ __launch_bounds__(256)
void cvt_bf16(const float* __restrict__ x,  const float* __restrict__ Wq,
              const float* __restrict__ Wk, const float* __restrict__ Wv,
              const float* __restrict__ Wo,
              bf16* __restrict__ xb, bf16* __restrict__ wqb, bf16* __restrict__ wkb,
              bf16* __restrict__ wvb, bf16* __restrict__ wob)
{
    const int idx = blockIdx.x * 256 + threadIdx.x;   // float4 index
    const float* src; bf16* dst; int off;
    if (idx < 1048576) { src = x; dst = xb; off = idx; }
    else {
        const int r = idx - 1048576;
        const int seg = r >> 18;          // 0..3  (262144 float4 per W)
        off = r & 262143;
        src = (seg == 0) ? Wq : (seg == 1) ? Wk : (seg == 2) ? Wv : Wo;
        dst = (seg == 0) ? wqb : (seg == 1) ? wkb : (seg == 2) ? wvb : wob;
    }
    const float4 v = ((const float4*)src)[off];
    bf16x4 o = {(bf16)v.x, (bf16)v.y, (bf16)v.z, (bf16)v.w};
    *(bf16x4*)(dst + (size_t)off * 4) = o;
}

// ---------------------------------------------------------------------------
// Kernel 1: fused QKV projection.  grid (32 Mtiles, 8 Ntiles, 3), 256 thr.
// BK=64, GLL staging with XOR swizzle.
// ---------------------------------------------------------------------------
__global__ __launch_bounds__(256, 3)
void qkv_gemm(const bf16* __restrict__ xb,
              const bf16* __restrict__ wqb, const float* __restrict__ bq,
              const bf16* __restrict__ wkb, const float* __restrict__ bk,
              const bf16* __restrict__ wvb, const float* __restrict__ bv,
              bf16* __restrict__ q_ws, bf16* __restrict__ k_ws, bf16* __restrict__ v_ws)
{
    const int z = blockIdx.z;
    const bf16*  W    = (z == 0) ? wqb : (z == 1) ? wkb : wvb;
    const float* bias = (z == 0) ? bq  : (z == 1) ? bk  : bv;

    __shared__ bf16 As[128][64];   // unpadded (GLL); swizzled columns
    __shared__ bf16 Bs[128][64];
    __shared__ char ebuf[17408];   // epilogue: Et[128][68] bf16 OR Vt[64][132] bf16
    bf16 (*Et)[68]  = (bf16(*)[68])ebuf;
    bf16 (*Vt)[132] = (bf16(*)[132])ebuf;

    const int m0 = blockIdx.x * 128;
    const int n0 = blockIdx.y * 128;
    const int t    = threadIdx.x;
    const int wave = t >> 6;
    const int lane = t & 63;
    const int lr   = lane & 15;
    const int quad = lane >> 4;
    const int wm = (wave & 1) * 64;
    const int wn = (wave >> 1) * 64;

    const int srow8 = lane >> 3;
    const int pcol  = (lane & 7) * 8;
    const int gcol  = ((lane & 7) ^ (lane >> 3)) * 8;   // swizzled global col
    const bf16* gaU[4]; const bf16* gbU[4]; bf16* laU[4]; bf16* lbU[4];
    #pragma unroll
    for (int u = 0; u < 4; u++) {
        const int row = wave * 32 + u * 8 + srow8;
        gaU[u] = xb + (size_t)(m0 + row) * 1024 + gcol;
        gbU[u] = W  + (size_t)(n0 + row) * 1024 + gcol;
        laU[u] = &As[row][pcol];
        lbU[u] = &Bs[row][pcol];
    }
    const int swA = (lr & 7) * 8;   // frag read swizzle for row wm+i*16+lr

    f32x4 acc[4][4] = {};

    for (int k0 = 0; k0 < 1024; k0 += 64) {
        #pragma unroll
        for (int u = 0; u < 4; u++) {
            GLL(gaU[u] + k0, laU[u]);
            GLL(gbU[u] + k0, lbU[u]);
        }
        __syncthreads();

        bf16x8 af[4][2], bfr[4][2];
        #pragma unroll
        for (int i = 0; i < 4; i++)
            #pragma unroll
            for (int kc = 0; kc < 2; kc++)
                af[i][kc] = *(const bf16x8*)&As[wm + i*16 + lr][(kc*32 + quad*8) ^ swA];
        #pragma unroll
        for (int j = 0; j < 4; j++)
            #pragma unroll
            for (int kc = 0; kc < 2; kc++)
                bfr[j][kc] = *(const bf16x8*)&Bs[wn + j*16 + lr][(kc*32 + quad*8) ^ swA];
        #pragma unroll
        for (int kc = 0; kc < 2; kc++)
            #pragma unroll
            for (int i = 0; i < 4; i++)
                #pragma unroll
                for (int j = 0; j < 4; j++)
                    acc[i][j] = MFMA32(af[i][kc], bfr[j][kc], acc[i][j]);
        __syncthreads();
    }

    const int bi = m0 >> 11, si0 = m0 & 2047;
    if (z < 2) {
        // q (pre-scaled 0.125) / k -> [b,h,s,dh] via LDS transpose
        bf16* hw = (z == 0) ? q_ws : k_ws;
        const float sc = (z == 0) ? 0.125f : 1.0f;
        #pragma unroll
        for (int ph = 0; ph < 2; ph++) {
            if ((wave >> 1) == ph) {
                #pragma unroll
                for (int j = 0; j < 4; j++) {
                    const float bb = bias[n0 + ph * 64 + j * 16 + lr];
                    #pragma unroll
                    for (int i = 0; i < 4; i++)
                        #pragma unroll
                        for (int r = 0; r < 4; r++)
                            Et[wm + i*16 + quad*4 + r][j*16 + lr] =
                                (bf16)((acc[i][j][r] + bb) * sc);
                }
            }
            __syncthreads();
            const int hh = (n0 >> 6) + ph;
            bf16* dst = hw + (((size_t)bi * 16 + hh) * 2048 + si0) * 64;
            const int row = t >> 1, cc = (t & 1) * 32;
            #pragma unroll
            for (int e = 0; e < 4; e++)
                *(bf16x8*)(dst + (size_t)row * 64 + cc + e * 8) =
                    *(const bf16x8*)&Et[row][cc + e * 8];
            __syncthreads();
        }
    } else {
        // v -> [b,h,dh,s] (transposed) via LDS
        #pragma unroll
        for (int ph = 0; ph < 2; ph++) {
            if ((wave >> 1) == ph) {
                #pragma unroll
                for (int j = 0; j < 4; j++) {
                    const float bb = bias[n0 + ph * 64 + j * 16 + lr];
                    #pragma unroll
                    for (int i = 0; i < 4; i++)
                        #pragma unroll
                        for (int r = 0; r < 4; r++)
                            Vt[j * 16 + lr][wm + i * 16 + quad * 4 + r] =
                                (bf16)(acc[i][j][r] + bb);
                }
            }
            __syncthreads();
            const int c  = t >> 2;             // local feature 0..63
            const int sc_ = (t & 3) * 32;
            const int col = n0 + ph * 64 + c;
            const int h = col >> 6, dh = col & 63;
            bf16* dst = v_ws + (((size_t)bi * 16 + h) * 64 + dh) * 2048 + si0 + sc_;
            #pragma unroll
            for (int e = 0; e < 4; e++)
                *(bf16x8*)(dst + e * 8) = *(const bf16x8*)&Vt[c][sc_ + e * 8];
            __syncthreads();
        }
    }
}

// ---------------------------------------------------------------------------
// Kernel 2: flash attention.  512 threads (8 waves), grid (32 bh, 16 qt) —
// XCD-swizzled: all q-tiles of a head share linear-id % 8.  Block = 128 Q
// rows; wave owns 16 (qrow=lane&15).  S^T = K.Q^T; softmaxed sacc is the
// B-operand of the 16x16x16 PV MFMA (O^T = V^T.P^T); stats per-lane.
// LDS: Ks[128][72] 18KB + Vs[64][140] 17.5KB = 35.9KB -> 4 blocks/CU.
// ---------------------------------------------------------------------------
__global__ __launch_bounds__(512, 4)
void attn(const bf16* __restrict__ q_ws, const bf16* __restrict__ k_ws,
          const bf16* __restrict__ v_ws, bf16* __restrict__ o_ws)
{
    const int bh = blockIdx.x;           // b*16+h   (XCD = bh % 8)
    const int qt = blockIdx.y;
    const int b_ = bh >> 4, h = bh & 15;

    const bf16* qbase = q_ws + (size_t)bh * 2048 * 64;
    const bf16* kbase = k_ws + (size_t)bh * 2048 * 64;
    const bf16* vbase = v_ws + (size_t)bh * 64 * 2048;  // [64][2048] V^T

    __shared__ bf16 Ks[128][72];     // [key][feat]
    __shared__ bf16 Vs[64][140];     // [feat][key]  (stride 70 dw: conflict-free b64)

    const int t    = threadIdx.x;
    const int wave = t >> 6;
    const int lane = t & 63;
    const int lr   = lane & 15;
    const int quad = lane >> 4;

    // Q fragments (pre-scaled by 0.125): B-operand of QK^T, n=qrow=lr
    bf16x8 aq[2];
    #pragma unroll
    for (int kc = 0; kc < 2; kc++)
        aq[kc] = *(const bf16x8*)(qbase +
            (size_t)(qt*128 + wave*16 + lr) * 64 + kc*32 + quad*8);

    float m_i = -1e30f, l_i = 0.f;       // stats for qrow = lr (per-lane)
    f32x4 o_accT[4] = {};                // O^T: rows feat, cols qrow=lr
    const float C = 1.44269504f;         // log2(e)

    // prefetch tile 0 into registers (512 threads -> 2 chunks each)
    bf16x8 kreg[2], vreg[2];
    #pragma unroll
    for (int u = 0; u < 2; u++) {
        const int c = t + u * 512;
        kreg[u] = *(const bf16x8*)(kbase + (size_t)c * 8);
        vreg[u] = *(const bf16x8*)(vbase + (size_t)(c >> 4) * 2048 + (c & 15) * 8);
    }

    for (int kt = 0; kt < 16; kt++) {
        __syncthreads();     // previous tile's LDS reads done
        #pragma unroll
        for (int u = 0; u < 2; u++) {
            const int c = t + u * 512;
            *(bf16x8*)&Ks[c >> 3][(c & 7) * 8]  = kreg[u];
            *(bf16x8*)&Vs[c >> 4][(c & 15) * 8] = vreg[u];
        }
        __syncthreads();
        if (kt < 15) {
            #pragma unroll
            for (int u = 0; u < 2; u++) {
                const int c = t + u * 512;
                kreg[u] = *(const bf16x8*)(kbase + (size_t)(kt+1) * 8192 + c * 8);
                vreg[u] = *(const bf16x8*)(vbase + (size_t)(c >> 4) * 2048
                                           + (kt+1) * 128 + (c & 15) * 8);
            }
        }

        // S^T: 8 key-frags x 16 qrows
        f32x4 sacc[8];
        #pragma unroll
        for (int j = 0; j < 8; j++) {
            bf16x8 kf0 = *(const bf16x8*)&Ks[j*16 + lr][quad*8];
            bf16x8 kf1 = *(const bf16x8*)&Ks[j*16 + lr][32 + quad*8];
            f32x4 a = {0.f, 0.f, 0.f, 0.f};
            a = MFMA32(kf0, aq[0], a);
            a = MFMA32(kf1, aq[1], a);
            sacc[j] = a;
        }

        // online softmax for qrow = lr (lane holds 32 of 128 keys)
        float m = -1e30f;
        #pragma unroll
        for (int j = 0; j < 8; j++)
            #pragma unroll
            for (int r = 0; r < 4; r++) m = fmaxf(m, sacc[j][r]);
        m = fmaxf(m, __shfl_xor(m, 16));
        m = fmaxf(m, __shfl_xor(m, 32));
        const float nm = fmaxf(m_i, m);
        const float al = exp2f((m_i - nm) * C);
        m_i = nm;
        const float nmc = nm * C;
        float rs = 0.f;
        #pragma unroll
        for (int j = 0; j < 8; j++)
            #pragma unroll
            for (int r = 0; r < 4; r++) {
                const float p = exp2f(fmaf(sacc[j][r], C, -nmc));
                sacc[j][r] = p;
                rs += p;
            }
        // rescale O^T: alpha is a per-lane scalar (cols are qrow=lr)
        #pragma unroll
        for (int n = 0; n < 4; n++)
            #pragma unroll
            for (int r = 0; r < 4; r++) o_accT[n][r] *= al;
        // l update (off the PV critical path)
        rs += __shfl_xor(rs, 16);
        rs += __shfl_xor(rs, 32);
        l_i = l_i * al + rs;

#if HAVE_MFMA16
        // O^T += V^T . P^T : A = V^T frag (8B from Vs), B = sacc directly
        #pragma unroll
        for (int j = 0; j < 8; j++) {
            pk4 pf;
            pf.h = bf16x4{(bf16)sacc[j][0], (bf16)sacc[j][1],
                          (bf16)sacc[j][2], (bf16)sacc[j][3]};
            #pragma unroll
            for (int fb = 0; fb < 4; fb++) {
                pk4 vf;
                *(unsigned long long*)vf.d =
                    *(const unsigned long long*)&Vs[fb*16 + lr][j*16 + quad*4];
                o_accT[fb] = MFMA16(vf.s, pf.s, o_accT[fb]);
            }
        }
#else
        // Fallback: build K=32 B-frags of P^T via shuffles, MFMA32 with A=V^T.
        unsigned int p0[8], p1[8];
        #pragma unroll
        for (int j = 0; j < 8; j++) {
            pk4 pf;
            pf.h = bf16x4{(bf16)sacc[j][0], (bf16)sacc[j][1],
                          (bf16)sacc[j][2], (bf16)sacc[j][3]};
            p0[j] = pf.d[0]; p1[j] = pf.d[1];
        }
        const int srcA = lr + 32 * (quad & 1);
        const int srcB = srcA + 16;
        const bool hi = (quad >> 1) != 0;
        #pragma unroll
        for (int c = 0; c < 4; c++) {
            unsigned int a0 = __shfl(p0[2*c], srcA), a1 = __shfl(p0[2*c+1], srcA);
            unsigned int b0 = __shfl(p1[2*c], srcA), b1 = __shfl(p1[2*c+1], srcA);
            unsigned int c0 = __shfl(p0[2*c], srcB), c1 = __shfl(p0[2*c+1], srcB);
            unsigned int d0 = __shfl(p1[2*c], srcB), d1 = __shfl(p1[2*c+1], srcB);
            unsigned int fr[4];
            fr[0] = hi ? a1 : a0;
            fr[1] = hi ? b1 : b0;
            fr[2] = hi ? c1 : c0;
            fr[3] = hi ? d1 : d0;
            bf16x8 pf8 = *(bf16x8*)fr;
            #pragma unroll
            for (int fb = 0; fb < 4; fb++) {
                bf16x8 vf8 = *(const bf16x8*)&Vs[fb*16 + lr][c*32 + quad*8];
                o_accT[fb] = MFMA32(vf8, pf8, o_accT[fb]);
            }
        }
#endif
    }

    // epilogue: divide, transpose through reused Ks LDS, coalesced stores
    __syncthreads();                      // all waves done reading Ks/Vs
    bf16 (*OsE)[68] = (bf16(*)[68])&Ks[0][0];    // 128 x 68 bf16 = 17.4KB
    const float inv = 1.0f / l_i;
    const int sil = wave * 16 + lr;       // local si 0..127
    #pragma unroll
    for (int fb = 0; fb < 4; fb++)
        #pragma unroll
        for (int r = 0; r < 4; r++)
            OsE[sil][fb*16 + quad*4 + r] = (bf16)(o_accT[fb][r] * inv);
    __syncthreads();
    const int row = t >> 2, seg = (t & 3) * 16;   // row 0..127
    bf16* dst = o_ws + ((size_t)b_ * 2048 + qt*128 + row) * 1024 + h*64 + seg;
    *(bf16x8*)(dst)     = *(const bf16x8*)&OsE[row][seg];
    *(bf16x8*)(dst + 8) = *(const bf16x8*)&OsE[row][seg + 8];
}

// ---------------------------------------------------------------------------
// Kernel 3: output projection.  64x128 tiles, grid (64,8), BK=64 + swizzle.
// ---------------------------------------------------------------------------
__global__ __launch_bounds__(256, 3)
void out_gemm(const bf16* __restrict__ o_ws,
              const bf16* __restrict__ wob, const float* __restrict__ bo,
              float* __restrict__ out)
{
    __shared__ bf16 As[64][64];
    __shared__ bf16 Bs[128][64];
    __shared__ float Ot[64][68];   // 17.4KB epilogue staging

    const int m0 = blockIdx.x * 64;
    const int n0 = blockIdx.y * 128;
    const int t    = threadIdx.x;
    const int wave = t >> 6;
    const int lane = t & 63;
    const int lr   = lane & 15;
    const int quad = lane >> 4;
    const int wm = (wave & 1) * 32;
    const int wn = (wave >> 1) * 64;

    const int srow8 = lane >> 3;
    const int pcol  = (lane & 7) * 8;
    const int gcol  = ((lane & 7) ^ (lane >> 3)) * 8;
    const bf16* gaU[2]; bf16* laU[2];
    #pragma unroll
    for (int u = 0; u < 2; u++) {
        const int row = wave * 16 + u * 8 + srow8;
        gaU[u] = o_ws + (size_t)(m0 + row) * 1024 + gcol;
        laU[u] = &As[row][pcol];
    }
    const bf16* gbU[4]; bf16* lbU[4];
    #pragma unroll
    for (int u = 0; u < 4; u++) {
        const int row = wave * 32 + u * 8 + srow8;
        gbU[u] = wob + (size_t)(n0 + row) * 1024 + gcol;
        lbU[u] = &Bs[row][pcol];
    }
    const int swA = (lr & 7) * 8;

    f32x4 acc[2][4] = {};

    for (int k0 = 0; k0 < 1024; k0 += 64) {
        #pragma unroll
        for (int u = 0; u < 2; u++) GLL(gaU[u] + k0, laU[u]);
        #pragma unroll
        for (int u = 0; u < 4; u++) GLL(gbU[u] + k0, lbU[u]);
        __syncthreads();

        bf16x8 af[2][2], bfr[4][2];
        #pragma unroll
        for (int i = 0; i < 2; i++)
            #pragma unroll
            for (int kc = 0; kc < 2; kc++)
                af[i][kc] = *(const bf16x8*)&As[wm + i*16 + lr][(kc*32 + quad*8) ^ swA];
        #pragma unroll
        for (int j = 0; j < 4; j++)
            #pragma unroll
            for (int kc = 0; kc < 2; kc++)
                bfr[j][kc] = *(const bf16x8*)&Bs[wn + j*16 + lr][(kc*32 + quad*8) ^ swA];
        #pragma unroll
        for (int kc = 0; kc < 2; kc++)
            #pragma unroll
            for (int i = 0; i < 2; i++)
                #pragma unroll
                for (int j = 0; j < 4; j++)
                    acc[i][j] = MFMA32(af[i][kc], bfr[j][kc], acc[i][j]);
        __syncthreads();
    }

    #pragma unroll
    for (int ph = 0; ph < 2; ph++) {
        if ((wave >> 1) == ph) {
            #pragma unroll
            for (int j = 0; j < 4; j++) {
                const float bb = bo[n0 + ph * 64 + j * 16 + lr];
                #pragma unroll
                for (int i = 0; i < 2; i++)
                    #pragma unroll
                    for (int r = 0; r < 4; r++)
                        Ot[wm + i*16 + quad*4 + r][j*16 + lr] = acc[i][j][r] + bb;
            }
        }
        __syncthreads();
        const int row = t >> 2, seg = (t & 3) * 16;
        float* dst = out + (size_t)(m0 + row) * 1024 + n0 + ph * 64 + seg;
        #pragma unroll
        for (int e = 0; e < 4; e++)
            *(float4*)(dst + e * 4) = *(const float4*)&Ot[row][seg + e * 4];
        __syncthreads();
    }
}

extern "C" void kernel_launch(void* const* d_in, const int* in_sizes, int n_in,
                              void* d_out, int out_size, void* d_ws, size_t ws_size,
                              hipStream_t stream) {
    (void)in_sizes; (void)n_in; (void)out_size; (void)ws_size;
    const float* x  = (const float*)d_in[0];
    const float* Wq = (const float*)d_in[1];
    const float* bq = (const float*)d_in[2];
    const float* Wk = (const float*)d_in[3];
    const float* bk = (const float*)d_in[4];
    const float* Wv = (const float*)d_in[5];
    const float* bv = (const float*)d_in[6];
    const float* Wo = (const float*)d_in[7];
    const float* bo = (const float*)d_in[8];
    float* out = (float*)d_out;

    char* ws = (char*)d_ws;
    const size_t MB = 1024 * 1024;
    bf16* xb   = (bf16*)(ws);
    bf16* wqb  = (bf16*)(ws + 8 * MB);
    bf16* wkb  = (bf16*)(ws + 10 * MB);
    bf16* wvb  = (bf16*)(ws + 12 * MB);
    bf16* wob  = (bf16*)(ws + 14 * MB);
    bf16* q_ws = (bf16*)(ws + 16 * MB);
    bf16* k_ws = (bf16*)(ws + 24 * MB);
    bf16* v_ws = (bf16*)(ws + 32 * MB);
    bf16* o_ws = (bf16*)(ws + 40 * MB);

    hipLaunchKernelGGL(cvt_bf16, dim3(8192), dim3(256), 0, stream,
                       x, Wq, Wk, Wv, Wo, xb, wqb, wkb, wvb, wob);
    hipLaunchKernelGGL(qkv_gemm, dim3(32, 8, 3), dim3(256), 0, stream,
                       xb, wqb, bq, wkb, bk, wvb, bv, q_ws, k_ws, v_ws);
    hipLaunchKernelGGL(attn, dim3(32, 16), dim3(512), 0, stream,
                       q_ws, k_ws, v_ws, o_ws);
    hipLaunchKernelGGL(out_gemm, dim3(64, 8), dim3(256), 0, stream,
                       o_ws, wob, bo, out);
}

// Round 10
// 204.361 us; speedup vs baseline: 1.1634x; 1.0406x over previous
//
#include <hip/hip_runtime.h>

// MHA: B=2 S=2048 D=1024 H=16 DH=64.  All GEMMs bf16 MFMA, fp32 acc.
// R10: attn restructured: (a) 32 qrows/wave (two 16-row sets) so every K/V
//      LDS fragment read feeds 2 MFMAs -> LDS read bytes per output halved
//      (2.1GB -> 1.05GB, ~15us floor); (b) double-buffered K/V LDS, ONE
//      barrier per tile, regs prefetched a full tile ahead.  Grid (32 bh,
//      8 qt) = 256 blocks = exactly 1 block/CU of 8 waves.
//      GEMM kernels unchanged from R6/R9.
// ws: xb 8MB @0 | wq/wk/wv/wo bf16 2MB each @8/10/12/14MB | q 8MB @16MB |
//     k 8MB @24MB | v^T 8MB @32MB [b,h,dh,s] | o 8MB @40MB  (needs 48MB ws)

typedef __bf16 bf16;
typedef bf16 bf16x8 __attribute__((ext_vector_type(8)));
typedef bf16 bf16x4 __attribute__((ext_vector_type(4)));
typedef short s16x4 __attribute__((ext_vector_type(4)));
typedef float f32x4 __attribute__((ext_vector_type(4)));

#define MFMA32(a, b, c) __builtin_amdgcn_mfma_f32_16x16x32_bf16(a, b, c, 0, 0, 0)

#if __has_builtin(__builtin_amdgcn_mfma_f32_16x16x16bf16_1k)
#define HAVE_MFMA16 1
#define MFMA16(a, b, c) __builtin_amdgcn_mfma_f32_16x16x16bf16_1k(a, b, c, 0, 0, 0)
#else
#define HAVE_MFMA16 0
#endif

// async global->LDS, 16B per lane; LDS dst must be wave-uniform base + lane*16
#define GLL(g, l) __builtin_amdgcn_global_load_lds(                              \
    (const __attribute__((address_space(1))) void*)(const void*)(g),             \
    (__attribute__((address_space(3))) void*)(void*)(l), 16, 0, 0)

union pk4 { bf16x4 h; s16x4 s; unsigned int d[2]; };

// ---------------------------------------------------------------------------
// Kernel 0: fp32 -> bf16 conversion of x and the four weight matrices.
// ---------------------------------------------------------------------------
__global__ __launch_bounds__(256)
void cvt_bf16(const float* __restrict__ x,  const float* __restrict__ Wq,
              const float* __restrict__ Wk, const float* __restrict__ Wv,
              const float* __restrict__ Wo,
              bf16* __restrict__ xb, bf16* __restrict__ wqb, bf16* __restrict__ wkb,
              bf16* __restrict__ wvb, bf16* __restrict__ wob)
{
    const int idx = blockIdx.x * 256 + threadIdx.x;   // float4 index
    const float* src; bf16* dst; int off;
    if (idx < 1048576) { src = x; dst = xb; off = idx; }
    else {
        const int r = idx - 1048576;
        const int seg = r >> 18;          // 0..3  (262144 float4 per W)
        off = r & 262143;
        src = (seg == 0) ? Wq : (seg == 1) ? Wk : (seg == 2) ? Wv : Wo;
        dst = (seg == 0) ? wqb : (seg == 1) ? wkb : (seg == 2) ? wvb : wob;
    }
    const float4 v = ((const float4*)src)[off];
    bf16x4 o = {(bf16)v.x, (bf16)v.y, (bf16)v.z, (bf16)v.w};
    *(bf16x4*)(dst + (size_t)off * 4) = o;
}

// ---------------------------------------------------------------------------
// Kernel 1: fused QKV projection.  grid (32 Mtiles, 8 Ntiles, 3), 256 thr.
// BK=64, GLL staging with XOR swizzle.
// ---------------------------------------------------------------------------
__global__ __launch_bounds__(256, 3)
void qkv_gemm(const bf16* __restrict__ xb,
              const bf16* __restrict__ wqb, const float* __restrict__ bq,
              const bf16* __restrict__ wkb, const float* __restrict__ bk,
              const bf16* __restrict__ wvb, const float* __restrict__ bv,
              bf16* __restrict__ q_ws, bf16* __restrict__ k_ws, bf16* __restrict__ v_ws)
{
    const int z = blockIdx.z;
    const bf16*  W    = (z == 0) ? wqb : (z == 1) ? wkb : wvb;
    const float* bias = (z == 0) ? bq  : (z == 1) ? bk  : bv;

    __shared__ bf16 As[128][64];   // unpadded (GLL); swizzled columns
    __shared__ bf16 Bs[128][64];
    __shared__ char ebuf[17408];   // epilogue: Et[128][68] bf16 OR Vt[64][132] bf16
    bf16 (*Et)[68]  = (bf16(*)[68])ebuf;
    bf16 (*Vt)[132] = (bf16(*)[132])ebuf;

    const int m0 = blockIdx.x * 128;
    const int n0 = blockIdx.y * 128;
    const int t    = threadIdx.x;
    const int wave = t >> 6;
    const int lane = t & 63;
    const int lr   = lane & 15;
    const int quad = lane >> 4;
    const int wm = (wave & 1) * 64;
    const int wn = (wave >> 1) * 64;

    const int srow8 = lane >> 3;
    const int pcol  = (lane & 7) * 8;
    const int gcol  = ((lane & 7) ^ (lane >> 3)) * 8;   // swizzled global col
    const bf16* gaU[4]; const bf16* gbU[4]; bf16* laU[4]; bf16* lbU[4];
    #pragma unroll
    for (int u = 0; u < 4; u++) {
        const int row = wave * 32 + u * 8 + srow8;
        gaU[u] = xb + (size_t)(m0 + row) * 1024 + gcol;
        gbU[u] = W  + (size_t)(n0 + row) * 1024 + gcol;
        laU[u] = &As[row][pcol];
        lbU[u] = &Bs[row][pcol];
    }
    const int swA = (lr & 7) * 8;   // frag read swizzle for row wm+i*16+lr

    f32x4 acc[4][4] = {};

    for (int k0 = 0; k0 < 1024; k0 += 64) {
        #pragma unroll
        for (int u = 0; u < 4; u++) {
            GLL(gaU[u] + k0, laU[u]);
            GLL(gbU[u] + k0, lbU[u]);
        }
        __syncthreads();

        bf16x8 af[4][2], bfr[4][2];
        #pragma unroll
        for (int i = 0; i < 4; i++)
            #pragma unroll
            for (int kc = 0; kc < 2; kc++)
                af[i][kc] = *(const bf16x8*)&As[wm + i*16 + lr][(kc*32 + quad*8) ^ swA];
        #pragma unroll
        for (int j = 0; j < 4; j++)
            #pragma unroll
            for (int kc = 0; kc < 2; kc++)
                bfr[j][kc] = *(const bf16x8*)&Bs[wn + j*16 + lr][(kc*32 + quad*8) ^ swA];
        #pragma unroll
        for (int kc = 0; kc < 2; kc++)
            #pragma unroll
            for (int i = 0; i < 4; i++)
                #pragma unroll
                for (int j = 0; j < 4; j++)
                    acc[i][j] = MFMA32(af[i][kc], bfr[j][kc], acc[i][j]);
        __syncthreads();
    }

    const int bi = m0 >> 11, si0 = m0 & 2047;
    if (z < 2) {
        // q (pre-scaled 0.125) / k -> [b,h,s,dh] via LDS transpose
        bf16* hw = (z == 0) ? q_ws : k_ws;
        const float sc = (z == 0) ? 0.125f : 1.0f;
        #pragma unroll
        for (int ph = 0; ph < 2; ph++) {
            if ((wave >> 1) == ph) {
                #pragma unroll
                for (int j = 0; j < 4; j++) {
                    const float bb = bias[n0 + ph * 64 + j * 16 + lr];
                    #pragma unroll
                    for (int i = 0; i < 4; i++)
                        #pragma unroll
                        for (int r = 0; r < 4; r++)
                            Et[wm + i*16 + quad*4 + r][j*16 + lr] =
                                (bf16)((acc[i][j][r] + bb) * sc);
                }
            }
            __syncthreads();
            const int hh = (n0 >> 6) + ph;
            bf16* dst = hw + (((size_t)bi * 16 + hh) * 2048 + si0) * 64;
            const int row = t >> 1, cc = (t & 1) * 32;
            #pragma unroll
            for (int e = 0; e < 4; e++)
                *(bf16x8*)(dst + (size_t)row * 64 + cc + e * 8) =
                    *(const bf16x8*)&Et[row][cc + e * 8];
            __syncthreads();
        }
    } else {
        // v -> [b,h,dh,s] (transposed) via LDS
        #pragma unroll
        for (int ph = 0; ph < 2; ph++) {
            if ((wave >> 1) == ph) {
                #pragma unroll
                for (int j = 0; j < 4; j++) {
                    const float bb = bias[n0 + ph * 64 + j * 16 + lr];
                    #pragma unroll
                    for (int i = 0; i < 4; i++)
                        #pragma unroll
                        for (int r = 0; r < 4; r++)
                            Vt[j * 16 + lr][wm + i * 16 + quad * 4 + r] =
                                (bf16)(acc[i][j][r] + bb);
                }
            }
            __syncthreads();
            const int c  = t >> 2;             // local feature 0..63
            const int sc_ = (t & 3) * 32;
            const int col = n0 + ph * 64 + c;
            const int h = col >> 6, dh = col & 63;
            bf16* dst = v_ws + (((size_t)bi * 16 + h) * 64 + dh) * 2048 + si0 + sc_;
            #pragma unroll
            for (int e = 0; e < 4; e++)
                *(bf16x8*)(dst + e * 8) = *(const bf16x8*)&Vt[c][sc_ + e * 8];
            __syncthreads();
        }
    }
}

// ---------------------------------------------------------------------------
// Kernel 2: flash attention.  512 threads (8 waves), grid (32 bh, 8 qt) =
// 256 blocks = 1 block/CU (XCD: all q-tiles of a head share id%8).
// Wave owns 32 qrows = TWO 16-row sets -> each K/V LDS fragment read feeds
// 2 MFMAs (LDS bytes per output halved).  Double-buffered K/V LDS: one
// barrier per tile; regs prefetched one full tile ahead.
// S^T = K.Q^T; softmaxed sacc is the B-operand of 16x16x16 PV (O^T=V^T.P^T).
// LDS: 2*(Ks 18KB + Vs 17.5KB) = 71KB.
// ---------------------------------------------------------------------------
__global__ __launch_bounds__(512, 2)
void attn(const bf16* __restrict__ q_ws, const bf16* __restrict__ k_ws,
          const bf16* __restrict__ v_ws, bf16* __restrict__ o_ws)
{
    const int bh = blockIdx.x;           // b*16+h   (XCD = bh % 8)
    const int qt = blockIdx.y;           // 0..7, 256 qrows per block
    const int b_ = bh >> 4, h = bh & 15;

    const bf16* qbase = q_ws + (size_t)bh * 2048 * 64;
    const bf16* kbase = k_ws + (size_t)bh * 2048 * 64;
    const bf16* vbase = v_ws + (size_t)bh * 64 * 2048;  // [64][2048] V^T

    __shared__ bf16 KsB[2 * 128 * 72];   // [buf][key][feat], stride 72
    __shared__ bf16 VsB[2 * 64 * 140];   // [buf][feat][key], stride 140

    const int t    = threadIdx.x;
    const int wave = t >> 6;
    const int lane = t & 63;
    const int lr   = lane & 15;
    const int quad = lane >> 4;

    // Q fragments (pre-scaled by 0.125): B-operand of QK^T, n=qrow=lr
    bf16x8 aq[2][2];
    #pragma unroll
    for (int s = 0; s < 2; s++)
        #pragma unroll
        for (int kc = 0; kc < 2; kc++)
            aq[s][kc] = *(const bf16x8*)(qbase +
                (size_t)(qt*256 + wave*32 + s*16 + lr) * 64 + kc*32 + quad*8);

    float m_i[2] = {-1e30f, -1e30f}, l_i[2] = {0.f, 0.f};
    f32x4 o_accT[2][4] = {};             // [set][featblk]: rows feat, cols qrow=lr
    const float C = 1.44269504f;         // log2(e)

    // register staging: 2 chunks per thread (1024 chunks per tile)
    const int c0 = t, c1 = t + 512;
    bf16x8 kreg[2], vreg[2];

    #define LOADREGS(kt_)                                                         \
        kreg[0] = *(const bf16x8*)(kbase + (size_t)(kt_) * 8192 + c0 * 8);        \
        kreg[1] = *(const bf16x8*)(kbase + (size_t)(kt_) * 8192 + c1 * 8);        \
        vreg[0] = *(const bf16x8*)(vbase + (size_t)(c0 >> 4) * 2048 + (kt_) * 128 \
                                   + (c0 & 15) * 8);                              \
        vreg[1] = *(const bf16x8*)(vbase + (size_t)(c1 >> 4) * 2048 + (kt_) * 128 \
                                   + (c1 & 15) * 8);

    #define STAGE(p_)                                                             \
        *(bf16x8*)&KsB[(p_) * 9216 + (c0 >> 3) * 72 + (c0 & 7) * 8]  = kreg[0];   \
        *(bf16x8*)&KsB[(p_) * 9216 + (c1 >> 3) * 72 + (c1 & 7) * 8]  = kreg[1];   \
        *(bf16x8*)&VsB[(p_) * 8960 + (c0 >> 4) * 140 + (c0 & 15) * 8] = vreg[0];  \
        *(bf16x8*)&VsB[(p_) * 8960 + (c1 >> 4) * 140 + (c1 & 15) * 8] = vreg[1];

    // prologue: tile0 -> buf0; tile1 -> regs
    LOADREGS(0);
    STAGE(0);
    LOADREGS(1);
    __syncthreads();

    for (int kt = 0; kt < 16; kt++) {
        const int p = kt & 1;
        // write next tile (regs hold kt+1) into the other buffer; then start
        // the global loads for kt+2 (a full tile of latency to hide)
        if (kt < 15) { STAGE(p ^ 1); }
        if (kt < 14) { LOADREGS(kt + 2); }
        const bf16* Ksp = &KsB[p * 9216];
        const bf16* Vsp = &VsB[p * 8960];

        // S^T: 8 key-frags x (2 sets x 16 qrows); K-frags shared across sets
        f32x4 sacc[2][8];
        #pragma unroll
        for (int j = 0; j < 8; j++) {
            bf16x8 kf0 = *(const bf16x8*)&Ksp[(j*16 + lr) * 72 + quad*8];
            bf16x8 kf1 = *(const bf16x8*)&Ksp[(j*16 + lr) * 72 + 32 + quad*8];
            #pragma unroll
            for (int s = 0; s < 2; s++) {
                f32x4 a = {0.f, 0.f, 0.f, 0.f};
                a = MFMA32(kf0, aq[s][0], a);
                a = MFMA32(kf1, aq[s][1], a);
                sacc[s][j] = a;
            }
        }

        // online softmax per set (qrow = lr, per-lane stats)
        #pragma unroll
        for (int s = 0; s < 2; s++) {
            float m = -1e30f;
            #pragma unroll
            for (int j = 0; j < 8; j++)
                #pragma unroll
                for (int r = 0; r < 4; r++) m = fmaxf(m, sacc[s][j][r]);
            m = fmaxf(m, __shfl_xor(m, 16));
            m = fmaxf(m, __shfl_xor(m, 32));
            const float nm = fmaxf(m_i[s], m);
            const float al = exp2f((m_i[s] - nm) * C);
            m_i[s] = nm;
            const float nmc = nm * C;
            float rs = 0.f;
            #pragma unroll
            for (int j = 0; j < 8; j++)
                #pragma unroll
                for (int r = 0; r < 4; r++) {
                    const float pv = exp2f(fmaf(sacc[s][j][r], C, -nmc));
                    sacc[s][j][r] = pv;
                    rs += pv;
                }
            #pragma unroll
            for (int n = 0; n < 4; n++)
                #pragma unroll
                for (int r = 0; r < 4; r++) o_accT[s][n][r] *= al;
            rs += __shfl_xor(rs, 16);
            rs += __shfl_xor(rs, 32);
            l_i[s] = l_i[s] * al + rs;
        }

#if HAVE_MFMA16
        // O^T += V^T . P^T : each V-frag read (b64) feeds both sets' MFMAs
        #pragma unroll
        for (int j = 0; j < 8; j++) {
            pk4 pf0, pf1;
            pf0.h = bf16x4{(bf16)sacc[0][j][0], (bf16)sacc[0][j][1],
                           (bf16)sacc[0][j][2], (bf16)sacc[0][j][3]};
            pf1.h = bf16x4{(bf16)sacc[1][j][0], (bf16)sacc[1][j][1],
                           (bf16)sacc[1][j][2], (bf16)sacc[1][j][3]};
            #pragma unroll
            for (int fb = 0; fb < 4; fb++) {
                pk4 vf;
                *(unsigned long long*)vf.d = *(const unsigned long long*)
                    &Vsp[(fb*16 + lr) * 140 + j*16 + quad*4];
                o_accT[0][fb] = MFMA16(vf.s, pf0.s, o_accT[0][fb]);
                o_accT[1][fb] = MFMA16(vf.s, pf1.s, o_accT[1][fb]);
            }
        }
#else
        // Fallback: shuffle-built K=32 P^T B-frags, MFMA32 with A=V^T (2x b64)
        #pragma unroll
        for (int s = 0; s < 2; s++) {
            unsigned int p0[8], p1[8];
            #pragma unroll
            for (int j = 0; j < 8; j++) {
                pk4 pf;
                pf.h = bf16x4{(bf16)sacc[s][j][0], (bf16)sacc[s][j][1],
                              (bf16)sacc[s][j][2], (bf16)sacc[s][j][3]};
                p0[j] = pf.d[0]; p1[j] = pf.d[1];
            }
            const int srcA = lr + 32 * (quad & 1);
            const int srcB = srcA + 16;
            const bool hi = (quad >> 1) != 0;
            #pragma unroll
            for (int c = 0; c < 4; c++) {
                unsigned int a0 = __shfl(p0[2*c], srcA), a1 = __shfl(p0[2*c+1], srcA);
                unsigned int b0 = __shfl(p1[2*c], srcA), b1 = __shfl(p1[2*c+1], srcA);
                unsigned int c0_ = __shfl(p0[2*c], srcB), c1_ = __shfl(p0[2*c+1], srcB);
                unsigned int d0 = __shfl(p1[2*c], srcB), d1 = __shfl(p1[2*c+1], srcB);
                unsigned int fr[4];
                fr[0] = hi ? a1 : a0;
                fr[1] = hi ? b1 : b0;
                fr[2] = hi ? c1_ : c0_;
                fr[3] = hi ? d1 : d0;
                bf16x8 pf8 = *(bf16x8*)fr;
                #pragma unroll
                for (int fb = 0; fb < 4; fb++) {
                    unsigned long long w0 = *(const unsigned long long*)
                        &Vsp[(fb*16 + lr) * 140 + c*32 + quad*8];
                    unsigned long long w1 = *(const unsigned long long*)
                        &Vsp[(fb*16 + lr) * 140 + c*32 + quad*8 + 4];
                    unsigned long long vv[2] = {w0, w1};
                    bf16x8 vf8 = *(bf16x8*)vv;
                    o_accT[s][fb] = MFMA32(vf8, pf8, o_accT[s][fb]);
                }
            }
        }
#endif
        __syncthreads();   // all reads of buf p done; buf p^1 writes visible
    }

    // epilogue: per set, divide, transpose through reused KsB, coalesced store
    bf16 (*OsE)[68] = (bf16(*)[68])&KsB[0];    // 128 x 68 bf16 = 17.4KB
    #pragma unroll
    for (int s = 0; s < 2; s++) {
        const float inv = 1.0f / l_i[s];
        const int sil = wave * 16 + lr;        // local row 0..127 for this set
        #pragma unroll
        for (int fb = 0; fb < 4; fb++)
            #pragma unroll
            for (int r = 0; r < 4; r++)
                OsE[sil][fb*16 + quad*4 + r] = (bf16)(o_accT[s][fb][r] * inv);
        __syncthreads();
        const int row = t >> 2, seg = (t & 3) * 16;   // row 0..127
        const int grow = qt*256 + (row >> 4)*32 + s*16 + (row & 15);
        bf16* dst = o_ws + ((size_t)b_ * 2048 + grow) * 1024 + h*64 + seg;
        *(bf16x8*)(dst)     = *(const bf16x8*)&OsE[row][seg];
        *(bf16x8*)(dst + 8) = *(const bf16x8*)&OsE[row][seg + 8];
        if (s == 0) __syncthreads();
    }
    #undef LOADREGS
    #undef STAGE
}

// ---------------------------------------------------------------------------
// Kernel 3: output projection.  64x128 tiles, grid (64,8), BK=64 + swizzle.
// ---------------------------------------------------------------------------
__global__ __launch_bounds__(256, 3)
void out_gemm(const bf16* __restrict__ o_ws,
              const bf16* __restrict__ wob, const float* __restrict__ bo,
              float* __restrict__ out)
{
    __shared__ bf16 As[64][64];
    __shared__ bf16 Bs[128][64];
    __shared__ float Ot[64][68];   // 17.4KB epilogue staging

    const int m0 = blockIdx.x * 64;
    const int n0 = blockIdx.y * 128;
    const int t    = threadIdx.x;
    const int wave = t >> 6;
    const int lane = t & 63;
    const int lr   = lane & 15;
    const int quad = lane >> 4;
    const int wm = (wave & 1) * 32;
    const int wn = (wave >> 1) * 64;

    const int srow8 = lane >> 3;
    const int pcol  = (lane & 7) * 8;
    const int gcol  = ((lane & 7) ^ (lane >> 3)) * 8;
    const bf16* gaU[2]; bf16* laU[2];
    #pragma unroll
    for (int u = 0; u < 2; u++) {
        const int row = wave * 16 + u * 8 + srow8;
        gaU[u] = o_ws + (size_t)(m0 + row) * 1024 + gcol;
        laU[u] = &As[row][pcol];
    }
    const bf16* gbU[4]; bf16* lbU[4];
    #pragma unroll
    for (int u = 0; u < 4; u++) {
        const int row = wave * 32 + u * 8 + srow8;
        gbU[u] = wob + (size_t)(n0 + row) * 1024 + gcol;
        lbU[u] = &Bs[row][pcol];
    }
    const int swA = (lr & 7) * 8;

    f32x4 acc[2][4] = {};

    for (int k0 = 0; k0 < 1024; k0 += 64) {
        #pragma unroll
        for (int u = 0; u < 2; u++) GLL(gaU[u] + k0, laU[u]);
        #pragma unroll
        for (int u = 0; u < 4; u++) GLL(gbU[u] + k0, lbU[u]);
        __syncthreads();

        bf16x8 af[2][2], bfr[4][2];
        #pragma unroll
        for (int i = 0; i < 2; i++)
            #pragma unroll
            for (int kc = 0; kc < 2; kc++)
                af[i][kc] = *(const bf16x8*)&As[wm + i*16 + lr][(kc*32 + quad*8) ^ swA];
        #pragma unroll
        for (int j = 0; j < 4; j++)
            #pragma unroll
            for (int kc = 0; kc < 2; kc++)
                bfr[j][kc] = *(const bf16x8*)&Bs[wn + j*16 + lr][(kc*32 + quad*8) ^ swA];
        #pragma unroll
        for (int kc = 0; kc < 2; kc++)
            #pragma unroll
            for (int i = 0; i < 2; i++)
                #pragma unroll
                for (int j = 0; j < 4; j++)
                    acc[i][j] = MFMA32(af[i][kc], bfr[j][kc], acc[i][j]);
        __syncthreads();
    }

    #pragma unroll
    for (int ph = 0; ph < 2; ph++) {
        if ((wave >> 1) == ph) {
            #pragma unroll
            for (int j = 0; j < 4; j++) {
                const float bb = bo[n0 + ph * 64 + j * 16 + lr];
                #pragma unroll
                for (int i = 0; i < 2; i++)
                    #pragma unroll
                    for (int r = 0; r < 4; r++)
                        Ot[wm + i*16 + quad*4 + r][j*16 + lr] = acc[i][j][r] + bb;
            }
        }
        __syncthreads();
        const int row = t >> 2, seg = (t & 3) * 16;
        float* dst = out + (size_t)(m0 + row) * 1024 + n0 + ph * 64 + seg;
        #pragma unroll
        for (int e = 0; e < 4; e++)
            *(float4*)(dst + e * 4) = *(const float4*)&Ot[row][seg + e * 4];
        __syncthreads();
    }
}

extern "C" void kernel_launch(void* const* d_in, const int* in_sizes, int n_in,
                              void* d_out, int out_size, void* d_ws, size_t ws_size,
                              hipStream_t stream) {
    (void)in_sizes; (void)n_in; (void)out_size; (void)ws_size;
    const float* x  = (const float*)d_in[0];
    const float* Wq = (const float*)d_in[1];
    const float* bq = (const float*)d_in[2];
    const float* Wk = (const float*)d_in[3];
    const float* bk = (const float*)d_in[4];
    const float* Wv = (const float*)d_in[5];
    const float* bv = (const float*)d_in[6];
    const float* Wo = (const float*)d_in[7];
    const float* bo = (const float*)d_in[8];
    float* out = (float*)d_out;

    char* ws = (char*)d_ws;
    const size_t MB = 1024 * 1024;
    bf16* xb   = (bf16*)(ws);
    bf16* wqb  = (bf16*)(ws + 8 * MB);
    bf16* wkb  = (bf16*)(ws + 10 * MB);
    bf16* wvb  = (bf16*)(ws + 12 * MB);
    bf16* wob  = (bf16*)(ws + 14 * MB);
    bf16* q_ws = (bf16*)(ws + 16 * MB);
    bf16* k_ws = (bf16*)(ws + 24 * MB);
    bf16* v_ws = (bf16*)(ws + 32 * MB);
    bf16* o_ws = (bf16*)(ws + 40 * MB);

    hipLaunchKernelGGL(cvt_bf16, dim3(8192), dim3(256), 0, stream,
                       x, Wq, Wk, Wv, Wo, xb, wqb, wkb, wvb, wob);
    hipLaunchKernelGGL(qkv_gemm, dim3(32, 8, 3), dim3(256), 0, stream,
                       xb, wqb, bq, wkb, bk, wvb, bv, q_ws, k_ws, v_ws);
    hipLaunchKernelGGL(attn, dim3(32, 8), dim3(512), 0, stream,
                       q_ws, k_ws, v_ws, o_ws);
    hipLaunchKernelGGL(out_gemm, dim3(64, 8), dim3(256), 0, stream,
                       o_ws, wob, bo, out);
}